// Round 2
// baseline (561.456 us; speedup 1.0000x reference)
//
#include <hip/hip_runtime.h>

typedef _Float16 f16;
typedef __attribute__((ext_vector_type(2))) _Float16 f16x2;
typedef __attribute__((ext_vector_type(8))) _Float16 f16x8;
typedef __attribute__((ext_vector_type(4))) float f32x4;

#define MFMA16(a,b,c) __builtin_amdgcn_mfma_f32_16x16x32_f16(a,b,c,0,0,0)

constexpr int NSEQ = 64;    // 2*8*4
constexpr int P    = 256;   // tokens per sequence
constexpr int DIMF = 768;
constexpr int NH   = 12;
constexpr int DH   = 64;

__device__ __forceinline__ f16x8 cvt8(const float* p) {
    const float4 u = *(const float4*)p;
    const float4 w = *(const float4*)(p + 4);
    f16x2 a = __builtin_bit_cast(f16x2, __builtin_amdgcn_cvt_pkrtz(u.x, u.y));
    f16x2 b = __builtin_bit_cast(f16x2, __builtin_amdgcn_cvt_pkrtz(u.z, u.w));
    f16x2 c = __builtin_bit_cast(f16x2, __builtin_amdgcn_cvt_pkrtz(w.x, w.y));
    f16x2 d = __builtin_bit_cast(f16x2, __builtin_amdgcn_cvt_pkrtz(w.z, w.w));
    f16x8 r;
    r[0]=a[0]; r[1]=a[1]; r[2]=b[0]; r[3]=b[1];
    r[4]=c[0]; r[5]=c[1]; r[6]=d[0]; r[7]=d[1];
    return r;
}

// Projection: q = x@Wq^T + bq (likewise k, v). Per block: 128 token-rows,
// one head-group g (cols g*64..g*64+63 of each of Q,K,V).
// Outputs: q,k as [seq][h][p][64] fp16 ; v transposed as [seq][h][64][p] fp16.
__global__ __launch_bounds__(256) void proj_kernel(
    const float* __restrict__ x,
    const float* __restrict__ Wq, const float* __restrict__ bq,
    const float* __restrict__ Wk, const float* __restrict__ bk,
    const float* __restrict__ Wv, const float* __restrict__ bv,
    f16* __restrict__ qout, f16* __restrict__ kout, f16* __restrict__ vt)
{
    const int g    = blockIdx.x;          // head / col-group (12)
    const int rt   = blockIdx.y;          // 128-row tile (128)
    const int lane = threadIdx.x & 63;
    const int wave = threadIdx.x >> 6;
    const int lr   = lane & 15;
    const int lg   = lane >> 4;

    const int row0 = rt * 128 + wave * 32;   // this wave's first token row
    const int seq  = rt >> 1;
    const int p0   = (rt & 1) * 128;         // block's first p within seq

    f32x4 acc[3][2][4];
    #pragma unroll
    for (int m = 0; m < 3; ++m)
      #pragma unroll
      for (int r = 0; r < 2; ++r)
        #pragma unroll
        for (int t = 0; t < 4; ++t) acc[m][r][t] = (f32x4){0.f,0.f,0.f,0.f};

    const float* Wp[3] = {Wq, Wk, Wv};
    const float* xp0 = x + (size_t)(row0 + lr) * DIMF + lg * 8;
    const float* xp1 = xp0 + 16 * DIMF;
    const float* wp[3][4];
    #pragma unroll
    for (int m = 0; m < 3; ++m)
      #pragma unroll
      for (int t = 0; t < 4; ++t)
        wp[m][t] = Wp[m] + (size_t)(g*64 + t*16 + lr) * DIMF + lg * 8;

    for (int ko = 0; ko < DIMF; ko += 32) {
        f16x8 a0 = cvt8(xp0 + ko);
        f16x8 a1 = cvt8(xp1 + ko);
        #pragma unroll
        for (int m = 0; m < 3; ++m) {
            #pragma unroll
            for (int t = 0; t < 4; ++t) {
                f16x8 b = cvt8(wp[m][t] + ko);
                acc[m][0][t] = MFMA16(a0, b, acc[m][0][t]);
                acc[m][1][t] = MFMA16(a1, b, acc[m][1][t]);
            }
        }
    }

    // ---- epilogue: Q and K (row-major [seq][h][p][64]) ----
    #pragma unroll
    for (int m = 0; m < 2; ++m) {
        f16* __restrict__ dst = m ? kout : qout;
        const float* __restrict__ bp = m ? bk : bq;
        #pragma unroll
        for (int t = 0; t < 4; ++t) {
            const float bb = bp[g*64 + t*16 + lr];
            #pragma unroll
            for (int r = 0; r < 2; ++r)
                #pragma unroll
                for (int i = 0; i < 4; ++i) {
                    const int p = p0 + wave*32 + r*16 + lg*4 + i;
                    dst[((size_t)(seq*NH + g)*P + p)*DH + t*16 + lr] =
                        (f16)(acc[m][r][t][i] + bb);
                }
        }
    }

    // ---- epilogue: V -> LDS -> transposed store [seq][h][64][p] ----
    __shared__ f16 vlds[128][76];
    #pragma unroll
    for (int t = 0; t < 4; ++t) {
        const float bb = bv[g*64 + t*16 + lr];
        #pragma unroll
        for (int r = 0; r < 2; ++r)
            #pragma unroll
            for (int i = 0; i < 4; ++i)
                vlds[wave*32 + r*16 + lg*4 + i][t*16 + lr] =
                    (f16)(acc[2][r][t][i] + bb);
    }
    __syncthreads();
    const int d  = threadIdx.x & 63;
    const int pc = (threadIdx.x >> 6) * 32;
    f16* dstv = vt + ((size_t)(seq*NH + g)*DH + d)*P + p0 + pc;
    #pragma unroll
    for (int jj = 0; jj < 4; ++jj) {
        f16x8 vv;
        #pragma unroll
        for (int j2 = 0; j2 < 8; ++j2) vv[j2] = vlds[pc + jj*8 + j2][d];
        *(f16x8*)(dstv + jj*8) = vv;
    }
}

// Attention: one block per (seq, head, 64-row group); 4 waves, each wave owns
// 16 q-rows x 256 keys. S kept fully in registers; P transposed via per-wave
// XOR-swizzled LDS; V consumed from the transposed copy.
__global__ __launch_bounds__(256) void attn_kernel(
    const f16* __restrict__ q, const f16* __restrict__ k,
    const f16* __restrict__ vt, float* __restrict__ out)
{
    __shared__ __align__(16) char plds[4][16*512];
    const int bid  = blockIdx.x;
    const int rg   = bid & 3;
    const int head = (bid >> 2) % NH;
    const int seq  = bid / (4*NH);
    const int lane = threadIdx.x & 63;
    const int wave = threadIdx.x >> 6;
    const int lr   = lane & 15;
    const int lg   = lane >> 4;

    const f16* qh = q  + (size_t)(seq*NH + head)*P*DH;
    const f16* kh = k  + (size_t)(seq*NH + head)*P*DH;
    const f16* vh = vt + (size_t)(seq*NH + head)*DH*P;

    const int qr0 = rg*64 + wave*16;

    const f16x8 aq0 = *(const f16x8*)(qh + (qr0 + lr)*DH + lg*8);
    const f16x8 aq1 = *(const f16x8*)(qh + (qr0 + lr)*DH + 32 + lg*8);

    f32x4 s[16];
    #pragma unroll
    for (int t = 0; t < 16; ++t) s[t] = (f32x4){0.f,0.f,0.f,0.f};

    #pragma unroll
    for (int t = 0; t < 16; ++t) {
        f16x8 b0 = *(const f16x8*)(kh + (t*16 + lr)*DH + lg*8);
        f16x8 b1 = *(const f16x8*)(kh + (t*16 + lr)*DH + 32 + lg*8);
        s[t] = MFMA16(aq0, b0, s[t]);
        s[t] = MFMA16(aq1, b1, s[t]);
    }

    // row max (rows = lg*4+i, cols spread over 16 tiles and 16 lanes)
    float mx[4] = {-1e30f, -1e30f, -1e30f, -1e30f};
    #pragma unroll
    for (int t = 0; t < 16; ++t)
        #pragma unroll
        for (int i = 0; i < 4; ++i) mx[i] = fmaxf(mx[i], s[t][i]);
    #pragma unroll
    for (int st = 1; st < 16; st <<= 1)
        #pragma unroll
        for (int i = 0; i < 4; ++i) mx[i] = fmaxf(mx[i], __shfl_xor(mx[i], st));

    const float SCL = 0.125f * 1.44269504088896f;   // scale * log2(e)
    float rs[4] = {0.f, 0.f, 0.f, 0.f};
    char* pw = plds[wave];
    #pragma unroll
    for (int t = 0; t < 16; ++t)
        #pragma unroll
        for (int i = 0; i < 4; ++i) {
            float e = exp2f((s[t][i] - mx[i]) * SCL);
            rs[i] += e;
            const int r = lg*4 + i, c = t*16 + lr;
            *(f16*)(pw + r*512 + ((c*2) ^ ((r & 7) << 4))) = (f16)e;
        }
    #pragma unroll
    for (int st = 1; st < 16; st <<= 1)
        #pragma unroll
        for (int i = 0; i < 4; ++i) rs[i] += __shfl_xor(rs[i], st);

    f32x4 o[4];
    #pragma unroll
    for (int t = 0; t < 4; ++t) o[t] = (f32x4){0.f,0.f,0.f,0.f};
    #pragma unroll
    for (int ko = 0; ko < 8; ++ko) {
        f16x8 ap = *(const f16x8*)(pw + lr*512 + (((ko*32 + lg*8)*2) ^ ((lr & 7) << 4)));
        #pragma unroll
        for (int t = 0; t < 4; ++t) {
            f16x8 bv_ = *(const f16x8*)(vh + (t*16 + lr)*P + ko*32 + lg*8);
            o[t] = MFMA16(ap, bv_, o[t]);
        }
    }

    #pragma unroll
    for (int i = 0; i < 4; ++i) rs[i] = 1.f / rs[i];
    float* op = out + ((size_t)seq*P + qr0)*DIMF + head*DH;
    #pragma unroll
    for (int t = 0; t < 4; ++t)
        #pragma unroll
        for (int i = 0; i < 4; ++i)
            op[(lg*4 + i)*DIMF + t*16 + lr] = o[t][i] * rs[i];
}

extern "C" void kernel_launch(void* const* d_in, const int* in_sizes, int n_in,
                              void* d_out, int out_size, void* d_ws, size_t ws_size,
                              hipStream_t stream) {
    const float* x  = (const float*)d_in[0];
    const float* Wq = (const float*)d_in[1];
    const float* bq = (const float*)d_in[2];
    const float* Wk = (const float*)d_in[3];
    const float* bk = (const float*)d_in[4];
    const float* Wv = (const float*)d_in[5];
    const float* bv = (const float*)d_in[6];
    float* out = (float*)d_out;

    const size_t QSZ = (size_t)NSEQ * P * NH * DH;  // 16384*768
    f16* q  = (f16*)d_ws;
    f16* k  = q + QSZ;
    f16* vt = k + QSZ;

    proj_kernel<<<dim3(12, 128), 256, 0, stream>>>(x, Wq, bq, Wk, bk, Wv, bv, q, k, vt);
    attn_kernel<<<dim3(64 * NH * 4), 256, 0, stream>>>(q, k, vt, out);
}

// Round 3
// 211.157 us; speedup vs baseline: 2.6590x; 2.6590x over previous
//
#include <hip/hip_runtime.h>

typedef _Float16 f16;
typedef __attribute__((ext_vector_type(2))) _Float16 f16x2;
typedef __attribute__((ext_vector_type(8))) _Float16 f16x8;
typedef __attribute__((ext_vector_type(4))) float f32x4;

#define MFMA16(a,b,c) __builtin_amdgcn_mfma_f32_16x16x32_f16(a,b,c,0,0,0)

constexpr int NSEQ = 64;    // 2*8*4
constexpr int P    = 256;   // tokens per sequence
constexpr int DIMF = 768;
constexpr int NH   = 12;
constexpr int DH   = 64;
constexpr int M    = NSEQ * P;        // 16384
constexpr int NTOT = 3 * DIMF;        // 2304
constexpr size_t XSZ = (size_t)M * DIMF;        // 12.58M halves
constexpr size_t WSZ = (size_t)DIMF * DIMF;     // per matrix

__device__ __forceinline__ f16x8 cvt8(const float* p) {
    const float4 u = *(const float4*)p;
    const float4 w = *(const float4*)(p + 4);
    f16x2 a = __builtin_bit_cast(f16x2, __builtin_amdgcn_cvt_pkrtz(u.x, u.y));
    f16x2 b = __builtin_bit_cast(f16x2, __builtin_amdgcn_cvt_pkrtz(u.z, u.w));
    f16x2 c = __builtin_bit_cast(f16x2, __builtin_amdgcn_cvt_pkrtz(w.x, w.y));
    f16x2 d = __builtin_bit_cast(f16x2, __builtin_amdgcn_cvt_pkrtz(w.z, w.w));
    f16x8 r;
    r[0]=a[0]; r[1]=a[1]; r[2]=b[0]; r[3]=b[1];
    r[4]=c[0]; r[5]=c[1]; r[6]=d[0]; r[7]=d[1];
    return r;
}

__device__ __forceinline__ void gload16(const void* g, void* l) {
    __builtin_amdgcn_global_load_lds(
        (const __attribute__((address_space(1))) void*)g,
        (__attribute__((address_space(3))) void*)l, 16, 0, 0);
}

// ---- fp32 -> fp16 convert: x -> xh [16384][768]; Wq|Wk|Wv -> wh [2304][768]
__global__ __launch_bounds__(256) void conv_kernel(
    const float* __restrict__ x,
    const float* __restrict__ Wq, const float* __restrict__ Wk,
    const float* __restrict__ Wv,
    f16* __restrict__ xh, f16* __restrict__ wh)
{
    const size_t i8 = ((size_t)blockIdx.x * 256 + threadIdx.x) * 8;
    if (i8 < XSZ) {
        *(f16x8*)(xh + i8) = cvt8(x + i8);
    } else {
        const size_t j = i8 - XSZ;           // < 3*WSZ
        const int mtx = (int)(j / WSZ);
        const size_t r = j - (size_t)mtx * WSZ;
        const float* src = (mtx == 0 ? Wq : mtx == 1 ? Wk : Wv) + r;
        *(f16x8*)(wh + j) = cvt8(src);
    }
}

// ---- projection GEMM: C[16384][2304] = xh @ wh^T + bias, scattered epilogue.
// Block: 128(M) x 128(N) tile, BK=32, double-buffered LDS, 4 waves in 2x2.
__global__ __launch_bounds__(256) void proj_gemm(
    const f16* __restrict__ xh, const f16* __restrict__ wh,
    const float* __restrict__ bq, const float* __restrict__ bk,
    const float* __restrict__ bv,
    f16* __restrict__ qout, f16* __restrict__ kout, f16* __restrict__ vt)
{
    // staging: 2 bufs x (A 8KB + B 8KB) = 32KB ; epilogue tile 128x132 f16 = 33792B
    __shared__ __align__(16) char smem[128 * 132 * 2];
    const int nt = blockIdx.x;            // 0..17
    const int mt = blockIdx.y;            // 0..127
    const int tid  = threadIdx.x;
    const int lane = tid & 63;
    const int wave = tid >> 6;
    const int lr   = lane & 15;
    const int lg   = lane >> 4;
    const int wm   = wave >> 1;           // 0..1  (M half)
    const int wn   = wave & 1;            // 0..1  (N half)

    const int m0 = mt * 128;
    const int n0 = nt * 128;

    // staging thread map: chunk c in {0,1}: row = c*64 + tid/4, colgrp = tid%4
    // source col-group XOR-swizzled, LDS linear (dest = bufbase + tid*16 + c*4096)
    const int srow  = tid >> 2;
    const int scg   = tid & 3;
    const f16* gA0 = xh + (size_t)(m0 + srow) * DIMF + ((scg ^ ((srow >> 1) & 3)) * 8);
    const f16* gA1 = xh + (size_t)(m0 + 64 + srow) * DIMF + ((scg ^ (((srow + 64) >> 1) & 3)) * 8);
    const f16* gB0 = wh + (size_t)(n0 + srow) * DIMF + ((scg ^ ((srow >> 1) & 3)) * 8);
    const f16* gB1 = wh + (size_t)(n0 + 64 + srow) * DIMF + ((scg ^ (((srow + 64) >> 1) & 3)) * 8);

    f32x4 acc[4][4];
    #pragma unroll
    for (int a = 0; a < 4; ++a)
        #pragma unroll
        for (int b = 0; b < 4; ++b) acc[a][b] = (f32x4){0.f,0.f,0.f,0.f};

    // fragment read offsets (bytes) within a buffer, XOR-swizzled k-group
    int offA[4], offB[4];
    #pragma unroll
    for (int f = 0; f < 4; ++f) {
        const int rA = wm * 64 + f * 16 + lr;
        offA[f] = rA * 64 + ((lg ^ ((rA >> 1) & 3)) * 16);
        const int rB = wn * 64 + f * 16 + lr;
        offB[f] = 8192 + rB * 64 + ((lg ^ ((rB >> 1) & 3)) * 16);
    }

    #define STAGE(buf, kk) do {                                            \
        char* lb = smem + (buf) * 16384;                                   \
        gload16(gA0 + (kk), lb + tid * 16);                                \
        gload16(gA1 + (kk), lb + 4096 + tid * 16);                         \
        gload16(gB0 + (kk), lb + 8192 + tid * 16);                         \
        gload16(gB1 + (kk), lb + 12288 + tid * 16);                        \
    } while (0)

    STAGE(0, 0);
    __syncthreads();

    int buf = 0;
    for (int t = 0; t < 24; ++t) {
        if (t < 23) STAGE(buf ^ 1, (t + 1) * 32);
        const char* lb = smem + buf * 16384;
        f16x8 a[4], b[4];
        #pragma unroll
        for (int f = 0; f < 4; ++f) a[f] = *(const f16x8*)(lb + offA[f]);
        #pragma unroll
        for (int f = 0; f < 4; ++f) b[f] = *(const f16x8*)(lb + offB[f]);
        #pragma unroll
        for (int fa = 0; fa < 4; ++fa)
            #pragma unroll
            for (int fb = 0; fb < 4; ++fb)
                acc[fa][fb] = MFMA16(a[fa], b[fb], acc[fa][fb]);
        __syncthreads();
        buf ^= 1;
    }

    // ---- epilogue ----
    const int mat = nt / 6;               // 0=q 1=k 2=v
    const int h0  = (nt % 6) * 2;         // head pair
    const int seq = mt >> 1;
    const int p0  = (mt & 1) * 128;
    const float* __restrict__ bias = mat == 0 ? bq : mat == 1 ? bk : bv;

    f16 (*ep)[132] = (f16 (*)[132])smem;
    #pragma unroll
    for (int fb = 0; fb < 4; ++fb) {
        const int col = wn * 64 + fb * 16 + lr;
        const float bb = bias[h0 * 64 + col];
        #pragma unroll
        for (int fa = 0; fa < 4; ++fa)
            #pragma unroll
            for (int i = 0; i < 4; ++i)
                ep[wm * 64 + fa * 16 + lg * 4 + i][col] = (f16)(acc[fa][fb][i] + bb);
    }
    __syncthreads();

    if (mat < 2) {
        // q/k: [seq][h][p][64] ; row r of ep -> p = p0+r ; col half -> head
        f16* __restrict__ dst = (mat ? kout : qout);
        const int r = tid >> 1, half = tid & 1;
        f16* drow = dst + ((size_t)(seq * NH + h0 + half) * P + p0 + r) * DH;
        const f16* srow_ = &ep[r][half * 64];
        #pragma unroll
        for (int j = 0; j < 8; ++j)
            *(f16x8*)(drow + j * 8) = *(const f16x8*)(srow_ + j * 8);
    } else {
        // v: transposed [seq][h][64][p]
        const int col = tid >> 1, ph = tid & 1;
        const int hh = col >> 6, d = col & 63;
        f16* drow = vt + ((size_t)(seq * NH + h0 + hh) * DH + d) * P + p0 + ph * 64;
        #pragma unroll
        for (int u = 0; u < 8; ++u) {
            f16x8 vv;
            #pragma unroll
            for (int uu = 0; uu < 8; ++uu)
                vv[uu] = ep[ph * 64 + u * 8 + uu][col];
            *(f16x8*)(drow + u * 8) = vv;
        }
    }
    #undef STAGE
}

// ---- attention (unchanged from passing round) ----
__global__ __launch_bounds__(256) void attn_kernel(
    const f16* __restrict__ q, const f16* __restrict__ k,
    const f16* __restrict__ vt, float* __restrict__ out)
{
    __shared__ __align__(16) char plds[4][16*512];
    const int bid  = blockIdx.x;
    const int rg   = bid & 3;
    const int head = (bid >> 2) % NH;
    const int seq  = bid / (4*NH);
    const int lane = threadIdx.x & 63;
    const int wave = threadIdx.x >> 6;
    const int lr   = lane & 15;
    const int lg   = lane >> 4;

    const f16* qh = q  + (size_t)(seq*NH + head)*P*DH;
    const f16* kh = k  + (size_t)(seq*NH + head)*P*DH;
    const f16* vh = vt + (size_t)(seq*NH + head)*DH*P;

    const int qr0 = rg*64 + wave*16;

    const f16x8 aq0 = *(const f16x8*)(qh + (qr0 + lr)*DH + lg*8);
    const f16x8 aq1 = *(const f16x8*)(qh + (qr0 + lr)*DH + 32 + lg*8);

    f32x4 s[16];
    #pragma unroll
    for (int t = 0; t < 16; ++t) s[t] = (f32x4){0.f,0.f,0.f,0.f};

    #pragma unroll
    for (int t = 0; t < 16; ++t) {
        f16x8 b0 = *(const f16x8*)(kh + (t*16 + lr)*DH + lg*8);
        f16x8 b1 = *(const f16x8*)(kh + (t*16 + lr)*DH + 32 + lg*8);
        s[t] = MFMA16(aq0, b0, s[t]);
        s[t] = MFMA16(aq1, b1, s[t]);
    }

    float mx[4] = {-1e30f, -1e30f, -1e30f, -1e30f};
    #pragma unroll
    for (int t = 0; t < 16; ++t)
        #pragma unroll
        for (int i = 0; i < 4; ++i) mx[i] = fmaxf(mx[i], s[t][i]);
    #pragma unroll
    for (int st = 1; st < 16; st <<= 1)
        #pragma unroll
        for (int i = 0; i < 4; ++i) mx[i] = fmaxf(mx[i], __shfl_xor(mx[i], st));

    const float SCL = 0.125f * 1.44269504088896f;   // scale * log2(e)
    float rs[4] = {0.f, 0.f, 0.f, 0.f};
    char* pw = plds[wave];
    #pragma unroll
    for (int t = 0; t < 16; ++t)
        #pragma unroll
        for (int i = 0; i < 4; ++i) {
            float e = exp2f((s[t][i] - mx[i]) * SCL);
            rs[i] += e;
            const int r = lg*4 + i, c = t*16 + lr;
            *(f16*)(pw + r*512 + ((c*2) ^ ((r & 7) << 4))) = (f16)e;
        }
    #pragma unroll
    for (int st = 1; st < 16; st <<= 1)
        #pragma unroll
        for (int i = 0; i < 4; ++i) rs[i] += __shfl_xor(rs[i], st);

    f32x4 o[4];
    #pragma unroll
    for (int t = 0; t < 4; ++t) o[t] = (f32x4){0.f,0.f,0.f,0.f};
    #pragma unroll
    for (int ko = 0; ko < 8; ++ko) {
        f16x8 ap = *(const f16x8*)(pw + lr*512 + (((ko*32 + lg*8)*2) ^ ((lr & 7) << 4)));
        #pragma unroll
        for (int t = 0; t < 4; ++t) {
            f16x8 bv_ = *(const f16x8*)(vh + (t*16 + lr)*P + ko*32 + lg*8);
            o[t] = MFMA16(ap, bv_, o[t]);
        }
    }

    #pragma unroll
    for (int i = 0; i < 4; ++i) rs[i] = 1.f / rs[i];
    float* op = out + ((size_t)seq*P + qr0)*DIMF + head*DH;
    #pragma unroll
    for (int t = 0; t < 4; ++t)
        #pragma unroll
        for (int i = 0; i < 4; ++i)
            op[(lg*4 + i)*DIMF + t*16 + lr] = o[t][i] * rs[i];
}

extern "C" void kernel_launch(void* const* d_in, const int* in_sizes, int n_in,
                              void* d_out, int out_size, void* d_ws, size_t ws_size,
                              hipStream_t stream) {
    const float* x  = (const float*)d_in[0];
    const float* Wq = (const float*)d_in[1];
    const float* bq = (const float*)d_in[2];
    const float* Wk = (const float*)d_in[3];
    const float* bk = (const float*)d_in[4];
    const float* Wv = (const float*)d_in[5];
    const float* bv = (const float*)d_in[6];
    float* out = (float*)d_out;

    // fp16 staging for xh/wh lives in d_out (50MB; needs 28.4MB) — it is fully
    // consumed by proj_gemm before attn_kernel overwrites d_out with the result.
    f16* xh = (f16*)d_out;
    f16* wh = xh + XSZ;

    const size_t QSZ = (size_t)M * DIMF;      // 12.58M halves
    f16* q  = (f16*)d_ws;
    f16* k  = q + QSZ;
    f16* vt = k + QSZ;

    const int convThreads = (int)((XSZ + 3 * WSZ) / 8);   // 1794048
    conv_kernel<<<convThreads / 256, 256, 0, stream>>>(x, Wq, Wk, Wv, xh, wh);
    proj_gemm<<<dim3(NTOT / 128, M / 128), 256, 0, stream>>>(xh, wh, bq, bk, bv, q, k, vt);
    attn_kernel<<<dim3(NSEQ * NH * 4), 256, 0, stream>>>(q, k, vt, out);
}

// Round 5
// 145.071 us; speedup vs baseline: 3.8702x; 1.4555x over previous
//
#include <hip/hip_runtime.h>

typedef _Float16 f16;
typedef __attribute__((ext_vector_type(2))) _Float16 f16x2;
typedef __attribute__((ext_vector_type(8))) _Float16 f16x8;
typedef __attribute__((ext_vector_type(4))) float f32x4;

#define MFMA16(a,b,c) __builtin_amdgcn_mfma_f32_16x16x32_f16(a,b,c,0,0,0)

constexpr int NSEQ = 64;    // 2*8*4
constexpr int P    = 256;   // tokens per sequence
constexpr int DIMF = 768;
constexpr int NH   = 12;
constexpr int DH   = 64;
constexpr int M    = NSEQ * P;        // 16384
constexpr int NTOT = 3 * DIMF;        // 2304
constexpr size_t XSZ = (size_t)M * DIMF;        // 12.58M halves
constexpr size_t WSZ = (size_t)DIMF * DIMF;     // per matrix

__device__ __forceinline__ f16x8 cvt8(const float* p) {
    const float4 u = *(const float4*)p;
    const float4 w = *(const float4*)(p + 4);
    f16x2 a = __builtin_bit_cast(f16x2, __builtin_amdgcn_cvt_pkrtz(u.x, u.y));
    f16x2 b = __builtin_bit_cast(f16x2, __builtin_amdgcn_cvt_pkrtz(u.z, u.w));
    f16x2 c = __builtin_bit_cast(f16x2, __builtin_amdgcn_cvt_pkrtz(w.x, w.y));
    f16x2 d = __builtin_bit_cast(f16x2, __builtin_amdgcn_cvt_pkrtz(w.z, w.w));
    f16x8 r;
    r[0]=a[0]; r[1]=a[1]; r[2]=b[0]; r[3]=b[1];
    r[4]=c[0]; r[5]=c[1]; r[6]=d[0]; r[7]=d[1];
    return r;
}

__device__ __forceinline__ void gload16(const void* g, void* l) {
    __builtin_amdgcn_global_load_lds(
        (const __attribute__((address_space(1))) void*)g,
        (__attribute__((address_space(3))) void*)l, 16, 0, 0);
}

// ---- fp32 -> fp16 convert: x -> xh [16384][768]; Wq|Wk|Wv -> wh [2304][768]
__global__ __launch_bounds__(256) void conv_kernel(
    const float* __restrict__ x,
    const float* __restrict__ Wq, const float* __restrict__ Wk,
    const float* __restrict__ Wv,
    f16* __restrict__ xh, f16* __restrict__ wh)
{
    const size_t i8 = ((size_t)blockIdx.x * 256 + threadIdx.x) * 8;
    if (i8 < XSZ) {
        *(f16x8*)(xh + i8) = cvt8(x + i8);
    } else {
        const size_t j = i8 - XSZ;           // < 3*WSZ
        const int mtx = (int)(j / WSZ);
        const size_t r = j - (size_t)mtx * WSZ;
        const float* src = (mtx == 0 ? Wq : mtx == 1 ? Wk : Wv) + r;
        *(f16x8*)(wh + j) = cvt8(src);
    }
}

// ---- projection GEMM: C[16384][2304] = xh @ wh^T + bias, scattered epilogue.
__global__ __launch_bounds__(256) void proj_gemm(
    const f16* __restrict__ xh, const f16* __restrict__ wh,
    const float* __restrict__ bq, const float* __restrict__ bk,
    const float* __restrict__ bv,
    f16* __restrict__ qout, f16* __restrict__ kout, f16* __restrict__ vt)
{
    __shared__ __align__(16) char smem[128 * 132 * 2];
    const int nt = blockIdx.x;            // 0..17
    const int mt = blockIdx.y;            // 0..127
    const int tid  = threadIdx.x;
    const int lane = tid & 63;
    const int wave = tid >> 6;
    const int lr   = lane & 15;
    const int lg   = lane >> 4;
    const int wm   = wave >> 1;
    const int wn   = wave & 1;

    const int m0 = mt * 128;
    const int n0 = nt * 128;

    const int srow  = tid >> 2;
    const int scg   = tid & 3;
    const f16* gA0 = xh + (size_t)(m0 + srow) * DIMF + ((scg ^ ((srow >> 1) & 3)) * 8);
    const f16* gA1 = xh + (size_t)(m0 + 64 + srow) * DIMF + ((scg ^ (((srow + 64) >> 1) & 3)) * 8);
    const f16* gB0 = wh + (size_t)(n0 + srow) * DIMF + ((scg ^ ((srow >> 1) & 3)) * 8);
    const f16* gB1 = wh + (size_t)(n0 + 64 + srow) * DIMF + ((scg ^ (((srow + 64) >> 1) & 3)) * 8);

    f32x4 acc[4][4];
    #pragma unroll
    for (int a = 0; a < 4; ++a)
        #pragma unroll
        for (int b = 0; b < 4; ++b) acc[a][b] = (f32x4){0.f,0.f,0.f,0.f};

    int offA[4], offB[4];
    #pragma unroll
    for (int f = 0; f < 4; ++f) {
        const int rA = wm * 64 + f * 16 + lr;
        offA[f] = rA * 64 + ((lg ^ ((rA >> 1) & 3)) * 16);
        const int rB = wn * 64 + f * 16 + lr;
        offB[f] = 8192 + rB * 64 + ((lg ^ ((rB >> 1) & 3)) * 16);
    }

    #define STAGE(buf, kk) do {                                            \
        char* lb = smem + (buf) * 16384;                                   \
        gload16(gA0 + (kk), lb + tid * 16);                                \
        gload16(gA1 + (kk), lb + 4096 + tid * 16);                         \
        gload16(gB0 + (kk), lb + 8192 + tid * 16);                         \
        gload16(gB1 + (kk), lb + 12288 + tid * 16);                        \
    } while (0)

    STAGE(0, 0);
    __syncthreads();

    int buf = 0;
    for (int t = 0; t < 24; ++t) {
        if (t < 23) STAGE(buf ^ 1, (t + 1) * 32);
        const char* lb = smem + buf * 16384;
        f16x8 a[4], b[4];
        #pragma unroll
        for (int f = 0; f < 4; ++f) a[f] = *(const f16x8*)(lb + offA[f]);
        #pragma unroll
        for (int f = 0; f < 4; ++f) b[f] = *(const f16x8*)(lb + offB[f]);
        #pragma unroll
        for (int fa = 0; fa < 4; ++fa)
            #pragma unroll
            for (int fb = 0; fb < 4; ++fb)
                acc[fa][fb] = MFMA16(a[fa], b[fb], acc[fa][fb]);
        __syncthreads();
        buf ^= 1;
    }

    const int mat = nt / 6;               // 0=q 1=k 2=v
    const int h0  = (nt % 6) * 2;         // head pair
    const int seq = mt >> 1;
    const int p0  = (mt & 1) * 128;
    const float* __restrict__ bias = mat == 0 ? bq : mat == 1 ? bk : bv;

    f16 (*ep)[132] = (f16 (*)[132])smem;
    #pragma unroll
    for (int fb = 0; fb < 4; ++fb) {
        const int col = wn * 64 + fb * 16 + lr;
        const float bb = bias[h0 * 64 + col];
        #pragma unroll
        for (int fa = 0; fa < 4; ++fa)
            #pragma unroll
            for (int i = 0; i < 4; ++i)
                ep[wm * 64 + fa * 16 + lg * 4 + i][col] = (f16)(acc[fa][fb][i] + bb);
    }
    __syncthreads();

    if (mat < 2) {
        f16* __restrict__ dst = (mat ? kout : qout);
        const int r = tid >> 1, half = tid & 1;
        f16* drow = dst + ((size_t)(seq * NH + h0 + half) * P + p0 + r) * DH;
        const f16* srow_ = &ep[r][half * 64];
        #pragma unroll
        for (int j = 0; j < 8; ++j)
            *(f16x8*)(drow + j * 8) = *(const f16x8*)(srow_ + j * 8);
    } else {
        const int col = tid >> 1, ph = tid & 1;
        const int hh = col >> 6, d = col & 63;
        f16* drow = vt + ((size_t)(seq * NH + h0 + hh) * DH + d) * P + p0 + ph * 64;
        #pragma unroll
        for (int u = 0; u < 8; ++u) {
            f16x8 vv;
            #pragma unroll
            for (int uu = 0; uu < 8; ++uu)
                vv[uu] = ep[ph * 64 + u * 8 + uu][col];
            *(f16x8*)(drow + u * 8) = vv;
        }
    }
    #undef STAGE
}

// ---- attention v2: block = (seq, head, 128-row half); 8 waves x 16 q-rows.
// K and V^T staged in LDS once per block (pre-swizzled source, linear dest);
// P-bounce shrunk to a 2KB/wave quarter buffer. LDS 80KB -> 2 blocks/CU.
__global__ __launch_bounds__(512) void attn_kernel(
    const f16* __restrict__ q, const f16* __restrict__ k,
    const f16* __restrict__ vt, float* __restrict__ out)
{
    __shared__ __align__(16) char kl[32768];     // K  [256 rows][128B], chunk-swizzled
    __shared__ __align__(16) char vl[32768];     // V^T[ 64 rows][512B], chunk-swizzled
    __shared__ __align__(16) char pl[8][2048];   // per-wave P quarter [16 q][64 k]

    // XCD pairing: both halves of a (seq,head) land on the same XCD
    const int n = blockIdx.x;                    // 1536 = 8 * 192
    const int b = (n & 7) * 192 + (n >> 3);
    const int half = b & 1;
    const int head = (b >> 1) % NH;
    const int seq  = b / (2 * NH);

    const int tid  = threadIdx.x;
    const int lane = tid & 63;
    const int wave = tid >> 6;
    const int lr   = lane & 15;
    const int lg   = lane >> 4;

    const f16* qh = q  + (size_t)(seq*NH + head)*P*DH;
    const f16* kh = k  + (size_t)(seq*NH + head)*P*DH;
    const f16* vh = vt + (size_t)(seq*NH + head)*DH*P;

    // ---- stage K and V^T (global source pre-swizzled, LDS dest linear) ----
    {
        const int r0 = tid >> 3, ck = tid & 7;       // K: 64 rows / 8KB iter
        const int d0 = tid >> 5, cv = tid & 31;      // V: 16 rows / 8KB iter
        #pragma unroll
        for (int it = 0; it < 4; ++it) {
            const int row = it * 64 + r0;
            gload16(kh + row * 64 + ((ck ^ (row & 7)) * 8), kl + it * 8192 + tid * 16);
            const int d = it * 16 + d0;
            gload16(vh + d * 256 + (((cv & 24) | ((cv ^ d) & 7)) * 8), vl + it * 8192 + tid * 16);
        }
    }

    const int qr0 = half * 128 + wave * 16;
    const f16x8 aq0 = *(const f16x8*)(qh + (qr0 + lr) * DH + lg * 8);
    const f16x8 aq1 = *(const f16x8*)(qh + (qr0 + lr) * DH + 32 + lg * 8);

    __syncthreads();

    // ---- QK^T from LDS ----
    f32x4 s[16];
    #pragma unroll
    for (int t = 0; t < 16; ++t) s[t] = (f32x4){0.f,0.f,0.f,0.f};
    #pragma unroll
    for (int t = 0; t < 16; ++t) {
        const int row = t * 16 + lr;
        const f16x8 b0 = *(const f16x8*)(kl + row * 128 + ((lg ^ (row & 7)) * 16));
        const f16x8 b1 = *(const f16x8*)(kl + row * 128 + (((lg + 4) ^ (row & 7)) * 16));
        s[t] = MFMA16(aq0, b0, s[t]);
        s[t] = MFMA16(aq1, b1, s[t]);
    }

    // ---- softmax (rows r = lg*4+i live in 16 lanes lr) ----
    float mx[4] = {-1e30f, -1e30f, -1e30f, -1e30f};
    #pragma unroll
    for (int t = 0; t < 16; ++t)
        #pragma unroll
        for (int i = 0; i < 4; ++i) mx[i] = fmaxf(mx[i], s[t][i]);
    #pragma unroll
    for (int st = 1; st < 16; st <<= 1)
        #pragma unroll
        for (int i = 0; i < 4; ++i) mx[i] = fmaxf(mx[i], __shfl_xor(mx[i], st));

    const float SCL = 0.125f * 1.44269504088896f;   // scale * log2(e)
    float rs[4] = {0.f, 0.f, 0.f, 0.f};
    #pragma unroll
    for (int t = 0; t < 16; ++t)
        #pragma unroll
        for (int i = 0; i < 4; ++i) {
            const float e = exp2f((s[t][i] - mx[i]) * SCL);
            s[t][i] = e;
            rs[i] += e;
        }
    #pragma unroll
    for (int st = 1; st < 16; st <<= 1)
        #pragma unroll
        for (int i = 0; i < 4; ++i) rs[i] += __shfl_xor(rs[i], st);

    // ---- PV in 4 quarters of 64 keys through the 2KB wave-private buffer ----
    char* pw = pl[wave];
    f32x4 o[4];
    #pragma unroll
    for (int t = 0; t < 4; ++t) o[t] = (f32x4){0.f,0.f,0.f,0.f};

    #pragma unroll
    for (int qq = 0; qq < 4; ++qq) {
        #pragma unroll
        for (int tt = 0; tt < 4; ++tt) {
            const int t = qq * 4 + tt;
            #pragma unroll
            for (int i = 0; i < 4; ++i) {
                const int r = lg * 4 + i;
                const int klocal = tt * 16 + lr;
                *(f16*)(pw + r * 128 + ((klocal * 2) ^ ((r & 7) << 4))) = (f16)s[t][i];
            }
        }
        #pragma unroll
        for (int kol = 0; kol < 2; ++kol) {
            const f16x8 ap = *(const f16x8*)(pw + lr * 128 + (((kol * 4 + lg) ^ (lr & 7)) * 16));
            #pragma unroll
            for (int dt = 0; dt < 4; ++dt) {
                const int row = dt * 16 + lr;                       // d
                const int ch  = qq * 8 + kol * 4 + lg;              // 16B chunk in V row
                const f16x8 bv_ = *(const f16x8*)(vl + row * 512 + (((ch & 24) | ((ch ^ row) & 7)) * 16));
                o[dt] = MFMA16(ap, bv_, o[dt]);
            }
        }
    }

    #pragma unroll
    for (int i = 0; i < 4; ++i) rs[i] = 1.f / rs[i];
    float* op = out + ((size_t)seq * P + qr0) * DIMF + head * DH;
    #pragma unroll
    for (int t = 0; t < 4; ++t)
        #pragma unroll
        for (int i = 0; i < 4; ++i)
            op[(lg * 4 + i) * DIMF + t * 16 + lr] = o[t][i] * rs[i];
}

extern "C" void kernel_launch(void* const* d_in, const int* in_sizes, int n_in,
                              void* d_out, int out_size, void* d_ws, size_t ws_size,
                              hipStream_t stream) {
    const float* x  = (const float*)d_in[0];
    const float* Wq = (const float*)d_in[1];
    const float* bq = (const float*)d_in[2];
    const float* Wk = (const float*)d_in[3];
    const float* bk = (const float*)d_in[4];
    const float* Wv = (const float*)d_in[5];
    const float* bv = (const float*)d_in[6];
    float* out = (float*)d_out;

    f16* xh = (f16*)d_out;          // fp16 staging lives in d_out (consumed
    f16* wh = xh + XSZ;             // before attn overwrites it)

    const size_t QSZ = (size_t)M * DIMF;
    f16* q  = (f16*)d_ws;
    f16* k  = q + QSZ;
    f16* vt = k + QSZ;

    const int convThreads = (int)((XSZ + 3 * WSZ) / 8);
    conv_kernel<<<convThreads / 256, 256, 0, stream>>>(x, Wq, Wk, Wv, xh, wh);
    proj_gemm<<<dim3(NTOT / 128, M / 128), 256, 0, stream>>>(xh, wh, bq, bk, bv, q, k, vt);
    attn_kernel<<<dim3(NSEQ * NH * 2), 512, 0, stream>>>(q, k, vt, out);
}

// Round 6
// 122.663 us; speedup vs baseline: 4.5772x; 1.1827x over previous
//
#include <hip/hip_runtime.h>

typedef _Float16 f16;
typedef __attribute__((ext_vector_type(2))) _Float16 f16x2;
typedef __attribute__((ext_vector_type(8))) _Float16 f16x8;
typedef __attribute__((ext_vector_type(4))) float f32x4;

#define MFMA16(a,b,c) __builtin_amdgcn_mfma_f32_16x16x32_f16(a,b,c,0,0,0)

constexpr int NSEQ = 64;    // 2*8*4
constexpr int P    = 256;   // tokens per sequence
constexpr int DIMF = 768;
constexpr int NH   = 12;
constexpr int DH   = 64;
constexpr int M    = NSEQ * P;        // 16384
constexpr size_t XSZ = (size_t)M * DIMF;
constexpr size_t WSZ = (size_t)DIMF * DIMF;

__device__ __forceinline__ f16x8 cvt8(const float* p) {
    const float4 u = *(const float4*)p;
    const float4 w = *(const float4*)(p + 4);
    f16x2 a = __builtin_bit_cast(f16x2, __builtin_amdgcn_cvt_pkrtz(u.x, u.y));
    f16x2 b = __builtin_bit_cast(f16x2, __builtin_amdgcn_cvt_pkrtz(u.z, u.w));
    f16x2 c = __builtin_bit_cast(f16x2, __builtin_amdgcn_cvt_pkrtz(w.x, w.y));
    f16x2 d = __builtin_bit_cast(f16x2, __builtin_amdgcn_cvt_pkrtz(w.z, w.w));
    f16x8 r;
    r[0]=a[0]; r[1]=a[1]; r[2]=b[0]; r[3]=b[1];
    r[4]=c[0]; r[5]=c[1]; r[6]=d[0]; r[7]=d[1];
    return r;
}

__device__ __forceinline__ void gload16(const void* g, void* l) {
    __builtin_amdgcn_global_load_lds(
        (const __attribute__((address_space(1))) void*)g,
        (__attribute__((address_space(3))) void*)l, 16, 0, 0);
}

// ---- fp32 -> fp16 convert: x -> xh [16384][768]; Wq|Wk|Wv -> wh [2304][768]
__global__ __launch_bounds__(256) void conv_kernel(
    const float* __restrict__ x,
    const float* __restrict__ Wq, const float* __restrict__ Wk,
    const float* __restrict__ Wv,
    f16* __restrict__ xh, f16* __restrict__ wh)
{
    const size_t i8 = ((size_t)blockIdx.x * 256 + threadIdx.x) * 8;
    if (i8 < XSZ) {
        *(f16x8*)(xh + i8) = cvt8(x + i8);
    } else {
        const size_t j = i8 - XSZ;
        const int mtx = (int)(j / WSZ);
        const size_t r = j - (size_t)mtx * WSZ;
        const float* src = (mtx == 0 ? Wq : mtx == 1 ? Wk : Wv) + r;
        *(f16x8*)(wh + j) = cvt8(src);
    }
}

// ---- projection GEMM, 256x256 tile, BK=64, 8 waves (2M x 4N), phase-split
// schedule with counted vmcnt + raw barriers + setprio. LDS 128KB:
// [0,32K) A buf0 | [32K,64K) A buf1 | [64K,96K) B buf0 | [96K,128K) B buf1.
// LDS[row][chunk] holds global chunk (chunk ^ (row&7)) — source-side swizzle.
__global__ __launch_bounds__(512, 2) void proj_gemm(
    const f16* __restrict__ xh, const f16* __restrict__ wh,
    const float* __restrict__ bq, const float* __restrict__ bk,
    const float* __restrict__ bv,
    f16* __restrict__ qout, f16* __restrict__ kout, f16* __restrict__ vt)
{
    __shared__ __align__(16) char smem[131072];
    // grid 576 = 64(mt) x 9(nt); bijective XCD chunking (72 per XCD), nt fastest
    const int wg = (blockIdx.x & 7) * 72 + (blockIdx.x >> 3);
    const int nt = wg % 9;
    const int mt = wg / 9;
    const int m0 = mt * 256, n0 = nt * 256;

    const int tid  = threadIdx.x;
    const int lane = tid & 63;
    const int wave = tid >> 6;
    const int lr   = lane & 15;
    const int lg   = lane >> 4;
    const int wm   = wave >> 2;       // 0..1  (128-row half)
    const int wn   = wave & 3;        // 0..3  (64-col quarter)

    // staging source (per-thread, chunk-swizzled)
    const int srow = tid >> 3, scc = tid & 7;
    const f16* gA = xh + (size_t)(m0 + srow) * DIMF + (scc ^ (srow & 7)) * 8;
    const f16* gB = wh + (size_t)(n0 + srow) * DIMF + (scc ^ (srow & 7)) * 8;

    // fragment read bases (row&7 == lr&7 for all fragment rows)
    const int swz0 = (lg ^ (lr & 7)) * 16;
    const char* pA0 = smem + (wm * 128 + lr) * 128;
    const char* pB0 = smem + 65536 + (wn * 64 + lr) * 128;

    f32x4 acc[8][4];
    #pragma unroll
    for (int f = 0; f < 8; ++f)
        #pragma unroll
        for (int g = 0; g < 4; ++g) acc[f][g] = (f32x4){0.f,0.f,0.f,0.f};

    // prologue: stage tile 0 into buf0 (8 loads/thread)
    #pragma unroll
    for (int q = 0; q < 4; ++q) {
        gload16(gA + (size_t)q * (64*DIMF), smem + q*8192 + tid*16);
        gload16(gB + (size_t)q * (64*DIMF), smem + 65536 + q*8192 + tid*16);
    }

    f16x8 a[4][2], bf[2][2];

    #pragma unroll 2
    for (int kt = 0; kt < 12; ++kt) {
        const int b = kt & 1;
        const char* lA = pA0 + b * 32768;
        const char* lB = pB0 + b * 32768;
        char* sA = smem + (b ^ 1) * 32768;
        char* sB = sA + 65536;
        const f16* ga = gA + (kt + 1) * 64;
        const f16* gb = gB + (kt + 1) * 64;
        const bool st = kt < 11;

        __builtin_amdgcn_s_barrier();   // close prev tile's reads before staging

        // ---- phase 0: quadrant (A-low, B-low) ----
        if (st) { gload16(ga, sA + tid*16); gload16(gb, sB + tid*16); }
        if (st) asm volatile("s_waitcnt vmcnt(2)" ::: "memory");
        else    asm volatile("s_waitcnt vmcnt(0)" ::: "memory");
        __builtin_amdgcn_s_barrier();
        __builtin_amdgcn_sched_barrier(0);
        #pragma unroll
        for (int f = 0; f < 4; ++f) {
            a[f][0] = *(const f16x8*)(lA + f*2048 + swz0);
            a[f][1] = *(const f16x8*)(lA + f*2048 + (swz0 ^ 64));
        }
        #pragma unroll
        for (int f = 0; f < 2; ++f) {
            bf[f][0] = *(const f16x8*)(lB + f*2048 + swz0);
            bf[f][1] = *(const f16x8*)(lB + f*2048 + (swz0 ^ 64));
        }
        __builtin_amdgcn_s_setprio(1);
        #pragma unroll
        for (int f = 0; f < 4; ++f)
            #pragma unroll
            for (int g = 0; g < 2; ++g) {
                acc[f][g] = MFMA16(a[f][0], bf[g][0], acc[f][g]);
                acc[f][g] = MFMA16(a[f][1], bf[g][1], acc[f][g]);
            }
        __builtin_amdgcn_s_setprio(0);

        // ---- phase 1: (A-low, B-high) ----
        if (st) { gload16(ga + (size_t)(64*DIMF), sA + 8192 + tid*16);
                  gload16(gb + (size_t)(64*DIMF), sB + 8192 + tid*16); }
        #pragma unroll
        for (int f = 0; f < 2; ++f) {
            bf[f][0] = *(const f16x8*)(lB + (2+f)*2048 + swz0);
            bf[f][1] = *(const f16x8*)(lB + (2+f)*2048 + (swz0 ^ 64));
        }
        __builtin_amdgcn_s_barrier();
        __builtin_amdgcn_s_setprio(1);
        #pragma unroll
        for (int f = 0; f < 4; ++f)
            #pragma unroll
            for (int g = 0; g < 2; ++g) {
                acc[f][2+g] = MFMA16(a[f][0], bf[g][0], acc[f][2+g]);
                acc[f][2+g] = MFMA16(a[f][1], bf[g][1], acc[f][2+g]);
            }
        __builtin_amdgcn_s_setprio(0);

        // ---- phase 2: (A-high, B-high) ----
        if (st) { gload16(ga + (size_t)(128*DIMF), sA + 16384 + tid*16);
                  gload16(gb + (size_t)(128*DIMF), sB + 16384 + tid*16); }
        #pragma unroll
        for (int f = 0; f < 4; ++f) {
            a[f][0] = *(const f16x8*)(lA + (4+f)*2048 + swz0);
            a[f][1] = *(const f16x8*)(lA + (4+f)*2048 + (swz0 ^ 64));
        }
        __builtin_amdgcn_s_barrier();
        __builtin_amdgcn_s_setprio(1);
        #pragma unroll
        for (int f = 0; f < 4; ++f)
            #pragma unroll
            for (int g = 0; g < 2; ++g) {
                acc[4+f][2+g] = MFMA16(a[f][0], bf[g][0], acc[4+f][2+g]);
                acc[4+f][2+g] = MFMA16(a[f][1], bf[g][1], acc[4+f][2+g]);
            }
        __builtin_amdgcn_s_setprio(0);

        // ---- phase 3: (A-high, B-low re-read) ----
        if (st) { gload16(ga + (size_t)(192*DIMF), sA + 24576 + tid*16);
                  gload16(gb + (size_t)(192*DIMF), sB + 24576 + tid*16); }
        #pragma unroll
        for (int f = 0; f < 2; ++f) {
            bf[f][0] = *(const f16x8*)(lB + f*2048 + swz0);
            bf[f][1] = *(const f16x8*)(lB + f*2048 + (swz0 ^ 64));
        }
        __builtin_amdgcn_s_barrier();
        __builtin_amdgcn_s_setprio(1);
        #pragma unroll
        for (int f = 0; f < 4; ++f)
            #pragma unroll
            for (int g = 0; g < 2; ++g) {
                acc[4+f][g] = MFMA16(a[f][0], bf[g][0], acc[4+f][g]);
                acc[4+f][g] = MFMA16(a[f][1], bf[g][1], acc[4+f][g]);
            }
        __builtin_amdgcn_s_setprio(0);
    }

    __syncthreads();

    // ---- epilogue: 2-pass LDS bounce (128 rows x 256 cols per pass) ----
    const int mat = nt / 3;               // 0=q 1=k 2=v
    const int c0  = (nt % 3) * 256;       // col offset within matrix
    const int seq = mt;
    const float* __restrict__ bias = mat == 0 ? bq : mat == 1 ? bk : bv;
    float bb[4];
    #pragma unroll
    for (int g = 0; g < 4; ++g) bb[g] = bias[c0 + wn*64 + g*16 + lr];

    f16 (*ep)[264] = (f16 (*)[264])smem;
    #pragma unroll
    for (int hh = 0; hh < 2; ++hh) {
        if (wm == hh) {
            #pragma unroll
            for (int f = 0; f < 8; ++f)
                #pragma unroll
                for (int g = 0; g < 4; ++g)
                    #pragma unroll
                    for (int i = 0; i < 4; ++i)
                        ep[f*16 + lg*4 + i][wn*64 + g*16 + lr] =
                            (f16)(acc[f][g][i] + bb[g]);
        }
        __syncthreads();
        if (mat < 2) {
            f16* __restrict__ dst = mat ? kout : qout;
            const int r = tid >> 2;
            #pragma unroll
            for (int s = 0; s < 8; ++s) {
                const int ch = s*4 + (tid & 3);
                const int h  = (nt % 3) * 4 + (ch >> 3);
                const int d0 = (ch & 7) * 8;
                *(f16x8*)(dst + ((size_t)(seq*NH + h)*P + hh*128 + r)*DH + d0) =
                    *(const f16x8*)&ep[r][ch*8];
            }
        } else {
            const int col = tid >> 1, rg = tid & 1;
            const int h = (nt % 3) * 4 + (col >> 6), d = col & 63;
            f16* drow = vt + ((size_t)(seq*NH + h)*DH + d)*P + hh*128 + rg*64;
            #pragma unroll
            for (int u = 0; u < 8; ++u) {
                f16x8 vv;
                #pragma unroll
                for (int uu = 0; uu < 8; ++uu)
                    vv[uu] = ep[rg*64 + u*8 + uu][col];
                *(f16x8*)(drow + u*8) = vv;
            }
        }
        __syncthreads();
    }
}

// ---- attention (unchanged from passing round 5) ----
__global__ __launch_bounds__(512) void attn_kernel(
    const f16* __restrict__ q, const f16* __restrict__ k,
    const f16* __restrict__ vt, float* __restrict__ out)
{
    __shared__ __align__(16) char kl[32768];
    __shared__ __align__(16) char vl[32768];
    __shared__ __align__(16) char pl[8][2048];

    const int n = blockIdx.x;                    // 1536 = 8 * 192
    const int b = (n & 7) * 192 + (n >> 3);
    const int half = b & 1;
    const int head = (b >> 1) % NH;
    const int seq  = b / (2 * NH);

    const int tid  = threadIdx.x;
    const int lane = tid & 63;
    const int wave = tid >> 6;
    const int lr   = lane & 15;
    const int lg   = lane >> 4;

    const f16* qh = q  + (size_t)(seq*NH + head)*P*DH;
    const f16* kh = k  + (size_t)(seq*NH + head)*P*DH;
    const f16* vh = vt + (size_t)(seq*NH + head)*DH*P;

    {
        const int r0 = tid >> 3, ck = tid & 7;
        const int d0 = tid >> 5, cv = tid & 31;
        #pragma unroll
        for (int it = 0; it < 4; ++it) {
            const int row = it * 64 + r0;
            gload16(kh + row * 64 + ((ck ^ (row & 7)) * 8), kl + it * 8192 + tid * 16);
            const int d = it * 16 + d0;
            gload16(vh + d * 256 + (((cv & 24) | ((cv ^ d) & 7)) * 8), vl + it * 8192 + tid * 16);
        }
    }

    const int qr0 = half * 128 + wave * 16;
    const f16x8 aq0 = *(const f16x8*)(qh + (qr0 + lr) * DH + lg * 8);
    const f16x8 aq1 = *(const f16x8*)(qh + (qr0 + lr) * DH + 32 + lg * 8);

    __syncthreads();

    f32x4 s[16];
    #pragma unroll
    for (int t = 0; t < 16; ++t) s[t] = (f32x4){0.f,0.f,0.f,0.f};
    #pragma unroll
    for (int t = 0; t < 16; ++t) {
        const int row = t * 16 + lr;
        const f16x8 b0 = *(const f16x8*)(kl + row * 128 + ((lg ^ (row & 7)) * 16));
        const f16x8 b1 = *(const f16x8*)(kl + row * 128 + (((lg + 4) ^ (row & 7)) * 16));
        s[t] = MFMA16(aq0, b0, s[t]);
        s[t] = MFMA16(aq1, b1, s[t]);
    }

    float mx[4] = {-1e30f, -1e30f, -1e30f, -1e30f};
    #pragma unroll
    for (int t = 0; t < 16; ++t)
        #pragma unroll
        for (int i = 0; i < 4; ++i) mx[i] = fmaxf(mx[i], s[t][i]);
    #pragma unroll
    for (int st = 1; st < 16; st <<= 1)
        #pragma unroll
        for (int i = 0; i < 4; ++i) mx[i] = fmaxf(mx[i], __shfl_xor(mx[i], st));

    const float SCL = 0.125f * 1.44269504088896f;
    float rs[4] = {0.f, 0.f, 0.f, 0.f};
    #pragma unroll
    for (int t = 0; t < 16; ++t)
        #pragma unroll
        for (int i = 0; i < 4; ++i) {
            const float e = exp2f((s[t][i] - mx[i]) * SCL);
            s[t][i] = e;
            rs[i] += e;
        }
    #pragma unroll
    for (int st = 1; st < 16; st <<= 1)
        #pragma unroll
        for (int i = 0; i < 4; ++i) rs[i] += __shfl_xor(rs[i], st);

    char* pw = pl[wave];
    f32x4 o[4];
    #pragma unroll
    for (int t = 0; t < 4; ++t) o[t] = (f32x4){0.f,0.f,0.f,0.f};

    #pragma unroll
    for (int qq = 0; qq < 4; ++qq) {
        #pragma unroll
        for (int tt = 0; tt < 4; ++tt) {
            const int t = qq * 4 + tt;
            #pragma unroll
            for (int i = 0; i < 4; ++i) {
                const int r = lg * 4 + i;
                const int klocal = tt * 16 + lr;
                *(f16*)(pw + r * 128 + ((klocal * 2) ^ ((r & 7) << 4))) = (f16)s[t][i];
            }
        }
        #pragma unroll
        for (int kol = 0; kol < 2; ++kol) {
            const f16x8 ap = *(const f16x8*)(pw + lr * 128 + (((kol * 4 + lg) ^ (lr & 7)) * 16));
            #pragma unroll
            for (int dt = 0; dt < 4; ++dt) {
                const int row = dt * 16 + lr;
                const int ch  = qq * 8 + kol * 4 + lg;
                const f16x8 bv_ = *(const f16x8*)(vl + row * 512 + (((ch & 24) | ((ch ^ row) & 7)) * 16));
                o[dt] = MFMA16(ap, bv_, o[dt]);
            }
        }
    }

    #pragma unroll
    for (int i = 0; i < 4; ++i) rs[i] = 1.f / rs[i];
    float* op = out + ((size_t)seq * P + qr0) * DIMF + head * DH;
    #pragma unroll
    for (int t = 0; t < 4; ++t)
        #pragma unroll
        for (int i = 0; i < 4; ++i)
            op[(lg * 4 + i) * DIMF + t * 16 + lr] = o[t][i] * rs[i];
}

extern "C" void kernel_launch(void* const* d_in, const int* in_sizes, int n_in,
                              void* d_out, int out_size, void* d_ws, size_t ws_size,
                              hipStream_t stream) {
    const float* x  = (const float*)d_in[0];
    const float* Wq = (const float*)d_in[1];
    const float* bq = (const float*)d_in[2];
    const float* Wk = (const float*)d_in[3];
    const float* bk = (const float*)d_in[4];
    const float* Wv = (const float*)d_in[5];
    const float* bv = (const float*)d_in[6];
    float* out = (float*)d_out;

    f16* xh = (f16*)d_out;          // fp16 staging lives in d_out (fully consumed
    f16* wh = xh + XSZ;             // by proj_gemm before attn overwrites d_out)

    const size_t QSZ = (size_t)M * DIMF;
    f16* q  = (f16*)d_ws;
    f16* k  = q + QSZ;
    f16* vt = k + QSZ;

    const int convThreads = (int)((XSZ + 3 * WSZ) / 8);
    conv_kernel<<<convThreads / 256, 256, 0, stream>>>(x, Wq, Wk, Wv, xh, wh);
    proj_gemm<<<dim3(576), 512, 0, stream>>>(xh, wh, bq, bk, bv, q, k, vt);
    attn_kernel<<<dim3(NSEQ * NH * 2), 512, 0, stream>>>(q, k, vt, out);
}

// Round 7
// 120.481 us; speedup vs baseline: 4.6601x; 1.0181x over previous
//
#include <hip/hip_runtime.h>

typedef _Float16 f16;
typedef __attribute__((ext_vector_type(2))) _Float16 f16x2;
typedef __attribute__((ext_vector_type(8))) _Float16 f16x8;
typedef __attribute__((ext_vector_type(4))) float f32x4;

#define MFMA16(a,b,c) __builtin_amdgcn_mfma_f32_16x16x32_f16(a,b,c,0,0,0)

constexpr int NSEQ = 64;    // 2*8*4
constexpr int P    = 256;   // tokens per sequence
constexpr int DIMF = 768;
constexpr int NH   = 12;
constexpr int DH   = 64;
constexpr int M    = NSEQ * P;        // 16384
constexpr size_t XSZ = (size_t)M * DIMF;
constexpr size_t WSZ = (size_t)DIMF * DIMF;

__device__ __forceinline__ f16x8 cvt8(const float* p) {
    const float4 u = *(const float4*)p;
    const float4 w = *(const float4*)(p + 4);
    f16x2 a = __builtin_bit_cast(f16x2, __builtin_amdgcn_cvt_pkrtz(u.x, u.y));
    f16x2 b = __builtin_bit_cast(f16x2, __builtin_amdgcn_cvt_pkrtz(u.z, u.w));
    f16x2 c = __builtin_bit_cast(f16x2, __builtin_amdgcn_cvt_pkrtz(w.x, w.y));
    f16x2 d = __builtin_bit_cast(f16x2, __builtin_amdgcn_cvt_pkrtz(w.z, w.w));
    f16x8 r;
    r[0]=a[0]; r[1]=a[1]; r[2]=b[0]; r[3]=b[1];
    r[4]=c[0]; r[5]=c[1]; r[6]=d[0]; r[7]=d[1];
    return r;
}

__device__ __forceinline__ void gload16(const void* g, void* l) {
    __builtin_amdgcn_global_load_lds(
        (const __attribute__((address_space(1))) void*)g,
        (__attribute__((address_space(3))) void*)l, 16, 0, 0);
}

// ---- fp32 -> fp16 convert ----
__global__ __launch_bounds__(256) void conv_kernel(
    const float* __restrict__ x,
    const float* __restrict__ Wq, const float* __restrict__ Wk,
    const float* __restrict__ Wv,
    f16* __restrict__ xh, f16* __restrict__ wh)
{
    const size_t i8 = ((size_t)blockIdx.x * 256 + threadIdx.x) * 8;
    if (i8 < XSZ) {
        *(f16x8*)(xh + i8) = cvt8(x + i8);
    } else {
        const size_t j = i8 - XSZ;
        const int mtx = (int)(j / WSZ);
        const size_t r = j - (size_t)mtx * WSZ;
        const float* src = (mtx == 0 ? Wq : mtx == 1 ? Wk : Wv) + r;
        *(f16x8*)(wh + j) = cvt8(src);
    }
}

// ---- projection GEMM: 256x256, BK=64, 8 waves; counted-vmcnt unit pipeline.
// LDS 128KB: A [2 buf][256 rows][128B] at 0; B same at 65536.
// Unit = 16KB half-tile (A0/A1/B0/B1), staged 4 phases before first read.
// Wave (wm 0..1, wn 0..3) owns rows {h*128 + wm*64 ..+64} x cols {bh*128 + wn*32 ..+32}.
__global__ __launch_bounds__(512, 1) void proj_gemm(
    const f16* __restrict__ xh, const f16* __restrict__ wh,
    const float* __restrict__ bq, const float* __restrict__ bk,
    const float* __restrict__ bv,
    f16* __restrict__ qout, f16* __restrict__ kout, f16* __restrict__ vt)
{
    __shared__ __align__(16) char smem[131072];
    const int wg = (blockIdx.x & 7) * 72 + (blockIdx.x >> 3);   // bijective (576 = 8*72)
    const int nt = wg % 9;
    const int mt = wg / 9;
    const int m0 = mt * 256, n0 = nt * 256;

    const int tid  = threadIdx.x;
    const int lane = tid & 63;
    const int wave = tid >> 6;
    const int lr   = lane & 15;
    const int lg   = lane >> 4;
    const int wm   = wave >> 2;       // 0..1 : 64-row strip within each 128-half
    const int wn   = wave & 3;        // 0..3 : 32-col strip within each 128-half

    // staging source (chunk-swizzled: LDS chunk c holds global chunk c ^ (row&7))
    const f16* srcA = xh + (size_t)(m0 + (tid >> 3)) * DIMF + ((tid & 7) ^ ((tid >> 3) & 7)) * 8;
    const f16* srcB = wh + (size_t)(n0 + (tid >> 3)) * DIMF + ((tid & 7) ^ ((tid >> 3) & 7)) * 8;
    char* dA = smem + tid * 16;
    char* dB = smem + 65536 + tid * 16;

    // fragment read bases
    const int swz0 = (lg ^ (lr & 7)) * 16;
    const char* rA = smem + (wm * 64 + lr) * 128;
    const char* rB = smem + 65536 + (wn * 32 + lr) * 128;

    f32x4 acc[2][4][2][2];
    #pragma unroll
    for (int ah = 0; ah < 2; ++ah)
      #pragma unroll
      for (int m = 0; m < 4; ++m)
        #pragma unroll
        for (int bh = 0; bh < 2; ++bh)
          #pragma unroll
          for (int n = 0; n < 2; ++n) acc[ah][m][bh][n] = (f32x4){0.f,0.f,0.f,0.f};

    f16x8 a[4][2], bf0[2][2], bf1[2][2];

    // unit staging: A-half H of tile T into buf B (2 x gload16 per thread)
    #define ST_A(H, T, B) do {                                                    \
        gload16(srcA + (size_t)((H)*128      ) * DIMF + (T)*64, dA + (B)*32768 + (H)*16384);          \
        gload16(srcA + (size_t)((H)*128 + 64 ) * DIMF + (T)*64, dA + (B)*32768 + (H)*16384 + 8192); } while (0)
    #define ST_B(H, T, B) do {                                                    \
        gload16(srcB + (size_t)((H)*128      ) * DIMF + (T)*64, dB + (B)*32768 + (H)*16384);          \
        gload16(srcB + (size_t)((H)*128 + 64 ) * DIMF + (T)*64, dB + (B)*32768 + (H)*16384 + 8192); } while (0)

    #define RD_A(H, B) do { _Pragma("unroll")                                      \
        for (int m = 0; m < 4; ++m) {                                              \
            a[m][0] = *(const f16x8*)(rA + (B)*32768 + (H)*16384 + m*2048 + swz0);        \
            a[m][1] = *(const f16x8*)(rA + (B)*32768 + (H)*16384 + m*2048 + (swz0^64)); } } while (0)
    #define RD_B(H, B, BF) do { _Pragma("unroll")                                  \
        for (int n = 0; n < 2; ++n) {                                              \
            BF[n][0] = *(const f16x8*)(rB + (B)*32768 + (H)*16384 + n*2048 + swz0);       \
            BF[n][1] = *(const f16x8*)(rB + (B)*32768 + (H)*16384 + n*2048 + (swz0^64)); } } while (0)

    #define CLUSTER(AH, BH, BF) do {                                               \
        __builtin_amdgcn_s_setprio(1);                                             \
        _Pragma("unroll") for (int m = 0; m < 4; ++m)                              \
        _Pragma("unroll") for (int n = 0; n < 2; ++n) {                            \
            acc[AH][m][BH][n] = MFMA16(a[m][0], BF[n][0], acc[AH][m][BH][n]);      \
            acc[AH][m][BH][n] = MFMA16(a[m][1], BF[n][1], acc[AH][m][BH][n]); }    \
        __builtin_amdgcn_s_setprio(0); } while (0)

    #define BAR  __builtin_amdgcn_s_barrier()
    #define LGKM asm volatile("s_waitcnt lgkmcnt(0)" ::: "memory")
    #define SCHB __builtin_amdgcn_sched_barrier(0)
    #define VM(N) asm volatile("s_waitcnt vmcnt(" #N ")" ::: "memory")

    // prologue: tile 0 -> buf0, full drain
    ST_A(0, 0, 0); ST_B(0, 0, 0); ST_B(1, 0, 0); ST_A(1, 0, 0);
    VM(0);
    BAR;

    for (int it = 0; it < 6; ++it) {
        const int T = 2 * it;
        const bool st2 = it < 5;           // stage tile T+2 (phases 4-6)

        // ---- ph0: (A0,B0) of T ; stage A0,B0(T+1)->buf1
        RD_A(0, 0); RD_B(0, 0, bf0);
        ST_A(0, T + 1, 1); ST_B(0, T + 1, 1);
        VM(6); BAR; LGKM; SCHB;
        CLUSTER(0, 0, bf0);

        // ---- ph1: (A0,B1) ; stage B1(T+1)
        RD_B(1, 0, bf1);
        ST_B(1, T + 1, 1);
        VM(6); BAR; LGKM; SCHB;
        CLUSTER(0, 1, bf1);

        // ---- ph2: (A1,B1) ; stage A1(T+1)
        RD_A(1, 0);
        ST_A(1, T + 1, 1);
        BAR; LGKM; SCHB;
        CLUSTER(1, 1, bf1);

        // ---- ph3: (A1,B0) — B0 frags held in regs since ph0
        VM(4); BAR; SCHB;
        CLUSTER(1, 0, bf0);

        // ---- ph4: tile T+1 (buf1): (A0,B0) ; stage A0,B0(T+2)->buf0
        RD_A(0, 1); RD_B(0, 1, bf0);
        if (st2) { ST_A(0, T + 2, 0); ST_B(0, T + 2, 0); }
        if (st2) { VM(6); } else { VM(2); }
        BAR; LGKM; SCHB;
        CLUSTER(0, 0, bf0);

        // ---- ph5: (A0,B1) ; stage B1(T+2)
        RD_B(1, 1, bf1);
        if (st2) ST_B(1, T + 2, 0);
        if (st2) { VM(6); } else { VM(0); }
        BAR; LGKM; SCHB;
        CLUSTER(0, 1, bf1);

        // ---- ph6: (A1,B1) ; stage A1(T+2)
        RD_A(1, 1);
        if (st2) ST_A(1, T + 2, 0);
        BAR; LGKM; SCHB;
        CLUSTER(1, 1, bf1);

        // ---- ph7: (A1,B0)
        VM(4); BAR; SCHB;
        CLUSTER(1, 0, bf0);
    }

    __syncthreads();

    // ---- epilogue: 2-pass LDS bounce (pass hh = 128-row half) ----
    const int mat = nt / 3;               // 0=q 1=k 2=v
    const int c0  = (nt % 3) * 256;
    const int seq = mt;
    const float* __restrict__ bias = mat == 0 ? bq : mat == 1 ? bk : bv;
    float bb[2][2];
    #pragma unroll
    for (int bh = 0; bh < 2; ++bh)
        #pragma unroll
        for (int n = 0; n < 2; ++n)
            bb[bh][n] = bias[c0 + bh*128 + wn*32 + n*16 + lr];

    f16 (*ep)[264] = (f16 (*)[264])smem;
    #pragma unroll
    for (int hh = 0; hh < 2; ++hh) {
        #pragma unroll
        for (int m = 0; m < 4; ++m)
            #pragma unroll
            for (int bh = 0; bh < 2; ++bh)
                #pragma unroll
                for (int n = 0; n < 2; ++n)
                    #pragma unroll
                    for (int i = 0; i < 4; ++i)
                        ep[wm*64 + m*16 + lg*4 + i][bh*128 + wn*32 + n*16 + lr] =
                            (f16)(acc[hh][m][bh][n][i] + bb[bh][n]);
        __syncthreads();
        if (mat < 2) {
            f16* __restrict__ dst = mat ? kout : qout;
            const int r = tid >> 2;
            #pragma unroll
            for (int s = 0; s < 8; ++s) {
                const int ch = s*4 + (tid & 3);
                const int h  = (nt % 3) * 4 + (ch >> 3);
                const int d0 = (ch & 7) * 8;
                *(f16x8*)(dst + ((size_t)(seq*NH + h)*P + hh*128 + r)*DH + d0) =
                    *(const f16x8*)&ep[r][ch*8];
            }
        } else {
            const int col = tid >> 1, rg = tid & 1;
            const int h = (nt % 3) * 4 + (col >> 6), d = col & 63;
            f16* drow = vt + ((size_t)(seq*NH + h)*DH + d)*P + hh*128 + rg*64;
            #pragma unroll
            for (int u = 0; u < 8; ++u) {
                f16x8 vv;
                #pragma unroll
                for (int uu = 0; uu < 8; ++uu)
                    vv[uu] = ep[rg*64 + u*8 + uu][col];
                *(f16x8*)(drow + u*8) = vv;
            }
        }
        __syncthreads();
    }
    #undef ST_A
    #undef ST_B
    #undef RD_A
    #undef RD_B
    #undef CLUSTER
    #undef BAR
    #undef LGKM
    #undef SCHB
    #undef VM
}

// ---- attention (unchanged from passing round 5) ----
__global__ __launch_bounds__(512) void attn_kernel(
    const f16* __restrict__ q, const f16* __restrict__ k,
    const f16* __restrict__ vt, float* __restrict__ out)
{
    __shared__ __align__(16) char kl[32768];
    __shared__ __align__(16) char vl[32768];
    __shared__ __align__(16) char pl[8][2048];

    const int n = blockIdx.x;                    // 1536 = 8 * 192
    const int b = (n & 7) * 192 + (n >> 3);
    const int half = b & 1;
    const int head = (b >> 1) % NH;
    const int seq  = b / (2 * NH);

    const int tid  = threadIdx.x;
    const int lane = tid & 63;
    const int wave = tid >> 6;
    const int lr   = lane & 15;
    const int lg   = lane >> 4;

    const f16* qh = q  + (size_t)(seq*NH + head)*P*DH;
    const f16* kh = k  + (size_t)(seq*NH + head)*P*DH;
    const f16* vh = vt + (size_t)(seq*NH + head)*DH*P;

    {
        const int r0 = tid >> 3, ck = tid & 7;
        const int d0 = tid >> 5, cv = tid & 31;
        #pragma unroll
        for (int it = 0; it < 4; ++it) {
            const int row = it * 64 + r0;
            gload16(kh + row * 64 + ((ck ^ (row & 7)) * 8), kl + it * 8192 + tid * 16);
            const int d = it * 16 + d0;
            gload16(vh + d * 256 + (((cv & 24) | ((cv ^ d) & 7)) * 8), vl + it * 8192 + tid * 16);
        }
    }

    const int qr0 = half * 128 + wave * 16;
    const f16x8 aq0 = *(const f16x8*)(qh + (qr0 + lr) * DH + lg * 8);
    const f16x8 aq1 = *(const f16x8*)(qh + (qr0 + lr) * DH + 32 + lg * 8);

    __syncthreads();

    f32x4 s[16];
    #pragma unroll
    for (int t = 0; t < 16; ++t) s[t] = (f32x4){0.f,0.f,0.f,0.f};
    #pragma unroll
    for (int t = 0; t < 16; ++t) {
        const int row = t * 16 + lr;
        const f16x8 b0 = *(const f16x8*)(kl + row * 128 + ((lg ^ (row & 7)) * 16));
        const f16x8 b1 = *(const f16x8*)(kl + row * 128 + (((lg + 4) ^ (row & 7)) * 16));
        s[t] = MFMA16(aq0, b0, s[t]);
        s[t] = MFMA16(aq1, b1, s[t]);
    }

    float mx[4] = {-1e30f, -1e30f, -1e30f, -1e30f};
    #pragma unroll
    for (int t = 0; t < 16; ++t)
        #pragma unroll
        for (int i = 0; i < 4; ++i) mx[i] = fmaxf(mx[i], s[t][i]);
    #pragma unroll
    for (int st = 1; st < 16; st <<= 1)
        #pragma unroll
        for (int i = 0; i < 4; ++i) mx[i] = fmaxf(mx[i], __shfl_xor(mx[i], st));

    const float SCL = 0.125f * 1.44269504088896f;
    float rs[4] = {0.f, 0.f, 0.f, 0.f};
    #pragma unroll
    for (int t = 0; t < 16; ++t)
        #pragma unroll
        for (int i = 0; i < 4; ++i) {
            const float e = exp2f((s[t][i] - mx[i]) * SCL);
            s[t][i] = e;
            rs[i] += e;
        }
    #pragma unroll
    for (int st = 1; st < 16; st <<= 1)
        #pragma unroll
        for (int i = 0; i < 4; ++i) rs[i] += __shfl_xor(rs[i], st);

    char* pw = pl[wave];
    f32x4 o[4];
    #pragma unroll
    for (int t = 0; t < 4; ++t) o[t] = (f32x4){0.f,0.f,0.f,0.f};

    #pragma unroll
    for (int qq = 0; qq < 4; ++qq) {
        #pragma unroll
        for (int tt = 0; tt < 4; ++tt) {
            const int t = qq * 4 + tt;
            #pragma unroll
            for (int i = 0; i < 4; ++i) {
                const int r = lg * 4 + i;
                const int klocal = tt * 16 + lr;
                *(f16*)(pw + r * 128 + ((klocal * 2) ^ ((r & 7) << 4))) = (f16)s[t][i];
            }
        }
        #pragma unroll
        for (int kol = 0; kol < 2; ++kol) {
            const f16x8 ap = *(const f16x8*)(pw + lr * 128 + (((kol * 4 + lg) ^ (lr & 7)) * 16));
            #pragma unroll
            for (int dt = 0; dt < 4; ++dt) {
                const int row = dt * 16 + lr;
                const int ch  = qq * 8 + kol * 4 + lg;
                const f16x8 bv_ = *(const f16x8*)(vl + row * 512 + (((ch & 24) | ((ch ^ row) & 7)) * 16));
                o[dt] = MFMA16(ap, bv_, o[dt]);
            }
        }
    }

    #pragma unroll
    for (int i = 0; i < 4; ++i) rs[i] = 1.f / rs[i];
    float* op = out + ((size_t)seq * P + qr0) * DIMF + head * DH;
    #pragma unroll
    for (int t = 0; t < 4; ++t)
        #pragma unroll
        for (int i = 0; i < 4; ++i)
            op[(lg * 4 + i) * DIMF + t * 16 + lr] = o[t][i] * rs[i];
}

extern "C" void kernel_launch(void* const* d_in, const int* in_sizes, int n_in,
                              void* d_out, int out_size, void* d_ws, size_t ws_size,
                              hipStream_t stream) {
    const float* x  = (const float*)d_in[0];
    const float* Wq = (const float*)d_in[1];
    const float* bq = (const float*)d_in[2];
    const float* Wk = (const float*)d_in[3];
    const float* bk = (const float*)d_in[4];
    const float* Wv = (const float*)d_in[5];
    const float* bv = (const float*)d_in[6];
    float* out = (float*)d_out;

    f16* xh = (f16*)d_out;          // fp16 staging lives in d_out (fully consumed
    f16* wh = xh + XSZ;             // by proj_gemm before attn overwrites d_out)

    const size_t QSZ = (size_t)M * DIMF;
    f16* q  = (f16*)d_ws;
    f16* k  = q + QSZ;
    f16* vt = k + QSZ;

    const int convThreads = (int)((XSZ + 3 * WSZ) / 8);
    conv_kernel<<<convThreads / 256, 256, 0, stream>>>(x, Wq, Wk, Wv, xh, wh);
    proj_gemm<<<dim3(576), 512, 0, stream>>>(xh, wh, bq, bk, bv, q, k, vt);
    attn_kernel<<<dim3(NSEQ * NH * 2), 512, 0, stream>>>(q, k, vt, out);
}